// Round 12
// baseline (443.424 us; speedup 1.0000x reference)
//
#include <hip/hip_runtime.h>
#include <hip/hip_bf16.h>
#include <cstdint>

// CapsuleFC: B=16, N_IN=256, D_IN=128, N_OUT=128, D_OUT=64
// MEASUREMENT ROUND: R11 pipeline byte-identical (272us) + pure-read probe with
// pass1's exact W access pattern appended LAST. T_probe = dur_total - 272us.
// Probe writes into out_part scratch (fully rewritten by pass3 each call).
//
// Ledger: pass1=222us@5.0TB/s invariant under queue depth (R9), VALU count
// (R10), occupancy (R11). This round discriminates pattern-cap vs interference.

#define BB 16
#define N_IN 256
#define D_IN 128
#define N_OUT 128
#define D_OUT 64
#define MD (N_OUT * D_OUT) /* 8192 */
#define NPB 2               /* n per block in pass1 */
#define NCH 32              /* n-chunks in pass3 (8 n each) */

// ---------------- Pass 0: transpose x -> xT[n][a][b] (b contiguous) ----------------
__global__ __launch_bounds__(256) void pass0_xT(
    const float* __restrict__ x, float* __restrict__ xT)
{
    const int idx = blockIdx.x * 256 + threadIdx.x;  // 524288 total
    const int b = idx & 15;
    const int a = (idx >> 4) & 127;
    const int n = idx >> 11;
    xT[idx] = x[((size_t)b * N_IN + n) * D_IN + a];  // write coalesced
}

// ---------------- Pass 1: votes (bf16x4), x staged in LDS (R11 exact) --------------
__global__ __launch_bounds__(256, 4) void pass1_votes(
    const float* __restrict__ xT, const float* __restrict__ W,
    uint2* __restrict__ votes4)
{
    __shared__ float xs[NPB * D_IN * BB]; // 16 KB
    const int t = threadIdx.x;
    const int chunk = blockIdx.x;   // 0..7
    const int ng = blockIdx.y;      // 0..127
    const int j = chunk * 1024 + t * 4;

    {
        const float4* src = reinterpret_cast<const float4*>(xT + ((size_t)ng * NPB << 11));
        float4* dst = reinterpret_cast<float4*>(xs);
#pragma unroll
        for (int r = 0; r < 4; ++r) dst[r * 256 + t] = src[r * 256 + t];
    }
    __syncthreads();

    for (int ni = 0; ni < NPB; ++ni) {
        const int n = ng * NPB + ni;
        const float4* __restrict__ Wp =
            reinterpret_cast<const float4*>(W + (size_t)n * D_IN * MD + j);

        float acc[BB][4];
#pragma unroll
        for (int b = 0; b < BB; ++b) {
            acc[b][0] = 0.f; acc[b][1] = 0.f; acc[b][2] = 0.f; acc[b][3] = 0.f;
        }

#pragma unroll 4
        for (int a = 0; a < D_IN; ++a) {
            const float4 w = Wp[(size_t)a * (MD / 4)];   // 1 KB/wave, coalesced
            const float4* xa = reinterpret_cast<const float4*>(xs + (ni * D_IN + a) * BB);
            const float4 x0 = xa[0], x1 = xa[1], x2 = xa[2], x3 = xa[3];
            const float xv[BB] = {x0.x, x0.y, x0.z, x0.w, x1.x, x1.y, x1.z, x1.w,
                                  x2.x, x2.y, x2.z, x2.w, x3.x, x3.y, x3.z, x3.w};
#pragma unroll
            for (int b = 0; b < BB; ++b) {
                acc[b][0] = fmaf(xv[b], w.x, acc[b][0]);
                acc[b][1] = fmaf(xv[b], w.y, acc[b][1]);
                acc[b][2] = fmaf(xv[b], w.z, acc[b][2]);
                acc[b][3] = fmaf(xv[b], w.w, acc[b][3]);
            }
        }

#pragma unroll
        for (int b = 0; b < BB; ++b) {
            union { __hip_bfloat16 h[4]; uint2 u; } pk;
            pk.h[0] = __float2bfloat16(acc[b][0]);
            pk.h[1] = __float2bfloat16(acc[b][1]);
            pk.h[2] = __float2bfloat16(acc[b][2]);
            pk.h[3] = __float2bfloat16(acc[b][3]);
            votes4[(((size_t)b * N_IN + n) * MD + j) >> 2] = pk.u;
        }
    }
}

// -------- Pass ncv-part: ncv_part[nh][b][j] = sum over 64 n of votes (fp32) --------
__global__ __launch_bounds__(256) void pass_ncv_part(
    const uint32_t* __restrict__ votes2, float* __restrict__ ncv_part)
{
    const int t = threadIdx.x;
    const int jc = blockIdx.x;   // 0..7
    const int nh = blockIdx.y;   // 0..3
    const int b  = blockIdx.z;   // 0..15
    const int j = jc * 1024 + t * 4;

    const uint2* vp = reinterpret_cast<const uint2*>(votes2) +
                      ((((size_t)b * N_IN + (size_t)nh * 64) * MD + j) >> 2);
    float s0 = 0.f, s1 = 0.f, s2 = 0.f, s3 = 0.f;
#pragma unroll 8
    for (int n = 0; n < 64; ++n) {
        const uint2 u = vp[(size_t)n * (MD / 4)];
        s0 += __uint_as_float(u.x << 16);
        s1 += __uint_as_float(u.x & 0xffff0000u);
        s2 += __uint_as_float(u.y << 16);
        s3 += __uint_as_float(u.y & 0xffff0000u);
    }
    float4 o; o.x = s0; o.y = s1; o.z = s2; o.w = s3;
    *reinterpret_cast<float4*>(ncv_part + ((size_t)nh * BB + b) * MD + j) = o;
}

// ---------------- Pass 3: amean + scores -> softmax -> qk -> partial reduce ----------
__global__ __launch_bounds__(256) void pass3_route(
    const __hip_bfloat16* __restrict__ votes, const float* __restrict__ ncv_part,
    const float* __restrict__ act, float* __restrict__ out_part,
    float* __restrict__ next_act_out, float* __restrict__ qk_out)
{
    __shared__ float red[4];
    __shared__ float aw[4];
    const int t = threadIdx.x;
    const int b = blockIdx.x;
    const int nc = blockIdx.y;
    const int m = t >> 1;
    const int half = t & 1;

    float av = act[b * N_IN + t];
#pragma unroll
    for (int off = 32; off; off >>= 1) av += __shfl_xor(av, off);
    if ((t & 63) == 0) aw[t >> 6] = av;
    __syncthreads();
    const float amean = (aw[0] + aw[1] + aw[2] + aw[3]) * (1.f / 256.f);
    const float qs = amean / (amean + 1e-10f);
    if (nc == 0 && half == 0) next_act_out[b * N_OUT + m] = amean;

    float nv[32], oacc[32];
    {
        const float4* p0 = reinterpret_cast<const float4*>(ncv_part + ((size_t)0 * BB + b) * MD + t * 32);
        const float4* p1 = reinterpret_cast<const float4*>(ncv_part + ((size_t)1 * BB + b) * MD + t * 32);
        const float4* p2 = reinterpret_cast<const float4*>(ncv_part + ((size_t)2 * BB + b) * MD + t * 32);
        const float4* p3 = reinterpret_cast<const float4*>(ncv_part + ((size_t)3 * BB + b) * MD + t * 32);
#pragma unroll
        for (int q = 0; q < 8; ++q) {
            const float4 a0 = p0[q], a1 = p1[q], a2 = p2[q], a3 = p3[q];
            nv[4 * q + 0] = (a0.x + a1.x) + (a2.x + a3.x);
            nv[4 * q + 1] = (a0.y + a1.y) + (a2.y + a3.y);
            nv[4 * q + 2] = (a0.z + a1.z) + (a2.z + a3.z);
            nv[4 * q + 3] = (a0.w + a1.w) + (a2.w + a3.w);
        }
#pragma unroll
        for (int i = 0; i < 32; ++i) { nv[i] *= (1.f / (float)N_OUT); oacc[i] = 0.f; }
    }

    const uint4* vbase = reinterpret_cast<const uint4*>(
        votes + (size_t)b * ((size_t)N_IN * MD) + (size_t)(nc * 8) * MD + t * 32);
    const size_t nstride = MD / 8;  // uint4 units per n

    uint4 buf[4];
#pragma unroll
    for (int q = 0; q < 4; ++q) buf[q] = vbase[q];

    for (int ni = 0; ni < 8; ++ni) {
        const int n = nc * 8 + ni;
        float vv[32];
#pragma unroll
        for (int q = 0; q < 4; ++q) {
            const uint32_t ww[4] = {buf[q].x, buf[q].y, buf[q].z, buf[q].w};
#pragma unroll
            for (int k = 0; k < 4; ++k) {
                vv[8 * q + 2 * k]     = __uint_as_float(ww[k] << 16);
                vv[8 * q + 2 * k + 1] = __uint_as_float(ww[k] & 0xffff0000u);
            }
        }
        if (ni < 7) {
            const uint4* vn = vbase + (size_t)(ni + 1) * nstride;
#pragma unroll
            for (int q = 0; q < 4; ++q) buf[q] = vn[q];
        }

        float p0 = 0.f, p1 = 0.f, p2 = 0.f, p3 = 0.f;
#pragma unroll
        for (int i = 0; i < 8; ++i) {
            p0 = fmaf(vv[4 * i + 0], nv[4 * i + 0], p0);
            p1 = fmaf(vv[4 * i + 1], nv[4 * i + 1], p1);
            p2 = fmaf(vv[4 * i + 2], nv[4 * i + 2], p2);
            p3 = fmaf(vv[4 * i + 3], nv[4 * i + 3], p3);
        }
        float sp = (p0 + p1) + (p2 + p3);
        sp += __shfl_xor(sp, 1);
        sp *= 0.125f; // 1/sqrt(D_OUT)

        const float p = __expf(sp);   // |scores| << 88, no max-shift needed
        float s = p;
#pragma unroll
        for (int off = 32; off; off >>= 1) s += __shfl_xor(s, off);
        if ((t & 63) == 0) red[t >> 6] = s;
        __syncthreads();
        const float ssum = (red[0] + red[1] + red[2] + red[3]) * 0.5f;
        __syncthreads();

        const float qk = (p / ssum) * qs;
        if (half == 0) qk_out[((size_t)(b * N_IN + n) << 7) + m] = qk;

        const float c = qk * act[b * N_IN + n];
#pragma unroll
        for (int i = 0; i < 32; ++i) oacc[i] = fmaf(c, vv[i], oacc[i]);
    }

    float4* op = reinterpret_cast<float4*>(out_part + ((size_t)nc * BB + b) * MD + t * 32);
#pragma unroll
    for (int q = 0; q < 8; ++q) {
        float4 o; o.x = oacc[4 * q]; o.y = oacc[4 * q + 1];
        o.z = oacc[4 * q + 2]; o.w = oacc[4 * q + 3];
        op[q] = o;
    }
}

// ---------------- Combine: out0[b][j] = sum over 32 nc partials ----------------
__global__ __launch_bounds__(256) void combine_out0(
    const float* __restrict__ out_part, float* __restrict__ out0)
{
    const int idx = blockIdx.x * 256 + threadIdx.x;  // 32768 float4s
    const int b = idx >> 11;          // /2048
    const int v4 = idx & 2047;
    const float4* p = reinterpret_cast<const float4*>(out_part);
    float4 s = {0.f, 0.f, 0.f, 0.f};
#pragma unroll 8
    for (int nc = 0; nc < NCH; ++nc) {
        const float4 f = p[((size_t)nc * BB + b) * (MD / 4) + v4];
        s.x += f.x; s.y += f.y; s.z += f.z; s.w += f.w;
    }
    reinterpret_cast<float4*>(out0)[idx] = s;
}

// ---------------- PROBE: pure read of W with pass1's exact pattern ----------------
// Same grid/stride walk as pass1; 4 adds per float4; 16B store/thread into scratch.
__global__ __launch_bounds__(256, 4) void probe_read(
    const float* __restrict__ W, float* __restrict__ sink)
{
    const int t = threadIdx.x;
    const int chunk = blockIdx.x;   // 0..7
    const int ng = blockIdx.y;      // 0..127
    const int j = chunk * 1024 + t * 4;

    float4 s = {0.f, 0.f, 0.f, 0.f};
    for (int ni = 0; ni < NPB; ++ni) {
        const int n = ng * NPB + ni;
        const float4* __restrict__ Wp =
            reinterpret_cast<const float4*>(W + (size_t)n * D_IN * MD + j);
#pragma unroll 4
        for (int a = 0; a < D_IN; ++a) {
            const float4 w = Wp[(size_t)a * (MD / 4)];
            s.x += w.x; s.y += w.y; s.z += w.z; s.w += w.w;
        }
    }
    reinterpret_cast<float4*>(sink)[(size_t)(ng * 8 + chunk) * 256 + t] = s;
}

extern "C" void kernel_launch(void* const* d_in, const int* in_sizes, int n_in,
                              void* d_out, int out_size, void* d_ws, size_t ws_size,
                              hipStream_t stream)
{
    const float* x   = (const float*)d_in[0];   // [16,256,128]
    const float* act = (const float*)d_in[1];   // [16,256]
    const float* W   = (const float*)d_in[2];   // [256,128,128,64]

    float* out      = (float*)d_out;
    float* out0     = out;                        // [16,128,64]  = 131072 elements
    float* next_act = out + 131072;               // [16,128]     = 2048
    float* qk_out   = out + 131072 + 2048;        // [16,256,128] = 524288

    // ws layout: votes bf16 64 MiB | ncv_part 2 MiB | out_part 16 MiB | xT 2 MiB
    __hip_bfloat16* votes = (__hip_bfloat16*)d_ws;
    float* ncv_part = (float*)((char*)d_ws + (size_t)67108864);
    float* out_part = (float*)((char*)d_ws + (size_t)67108864 + 2097152);
    float* xT       = (float*)((char*)d_ws + (size_t)67108864 + 2097152 + 16777216);

    pass0_xT<<<2048, 256, 0, stream>>>(x, xT);
    pass1_votes<<<dim3(8, 128), 256, 0, stream>>>(xT, W, (uint2*)votes);
    pass_ncv_part<<<dim3(8, 4, 16), 256, 0, stream>>>((const uint32_t*)votes, ncv_part);
    pass3_route<<<dim3(16, NCH), 256, 0, stream>>>(votes, ncv_part, act, out_part,
                                                   next_act, qk_out);
    combine_out0<<<128, 256, 0, stream>>>(out_part, out0);
    // PROBE last: writes into out_part scratch (pass3 fully rewrites it next call).
    probe_read<<<dim3(8, 128), 256, 0, stream>>>(W, out_part);
}

// Round 13
// 282.671 us; speedup vs baseline: 1.5687x; 1.5687x over previous
//
#include <hip/hip_runtime.h>
#include <hip/hip_bf16.h>
#include <cstdint>

// CapsuleFC: B=16, N_IN=256, D_IN=128, N_OUT=128, D_OUT=64
// R12 probe: W's access pattern alone streams at 6.28 TB/s (171us); pass1's 222us
// is compute-interleave friction. R13: global_load_lds staging of W with
// double-buffered tiles + counted vmcnt(4) + raw s_barrier (T3/T4 pattern).

#define BB 16
#define N_IN 256
#define D_IN 128
#define N_OUT 128
#define D_OUT 64
#define MD (N_OUT * D_OUT) /* 8192 */
#define NPB 2               /* n per block in pass1 */
#define NCH 32              /* n-chunks in pass3 (8 n each) */
#define TA 4                /* a-rows per W tile */
#define NT (D_IN / TA)      /* 32 tiles per n */

__device__ __forceinline__ void gload16(const float* g, float* l) {
    __builtin_amdgcn_global_load_lds(
        (const __attribute__((address_space(1))) void*)g,
        (__attribute__((address_space(3))) void*)l, 16, 0, 0);
}
#define VM4 asm volatile("s_waitcnt vmcnt(4)" ::: "memory")
#define VM0 asm volatile("s_waitcnt vmcnt(0)" ::: "memory")

// ---------------- Pass 0: transpose x -> xT[n][a][b] (b contiguous) ----------------
__global__ __launch_bounds__(256) void pass0_xT(
    const float* __restrict__ x, float* __restrict__ xT)
{
    const int idx = blockIdx.x * 256 + threadIdx.x;  // 524288 total
    const int b = idx & 15;
    const int a = (idx >> 4) & 127;
    const int n = idx >> 11;
    xT[idx] = x[((size_t)b * N_IN + n) * D_IN + a];  // write coalesced
}

// ------ Pass 1: votes (bf16x4); W staged via global_load_lds, dbuf + counted vmcnt ----
// grid (8 j-chunks of 1024, 128 n-groups of 2), block 256 (4 waves).
__global__ __launch_bounds__(256) void pass1_votes(
    const float* __restrict__ xT, const float* __restrict__ W,
    uint2* __restrict__ votes4)
{
    __shared__ float xs[NPB * D_IN * BB];  // 16 KB
    __shared__ float wb[2][TA * 1024];     // 2 x 16 KB W tiles
    const int t = threadIdx.x;
    const int wid = t >> 6, lane = t & 63;
    const int chunk = blockIdx.x;   // 0..7
    const int ng = blockIdx.y;      // 0..127
    const int jbase = chunk * 1024;
    const int j = jbase + t * 4;

    {
        const float4* src = reinterpret_cast<const float4*>(xT + ((size_t)ng * NPB << 11));
        float4* dst = reinterpret_cast<float4*>(xs);
#pragma unroll
        for (int r = 0; r < 4; ++r) dst[r * 256 + t] = src[r * 256 + t];
    }
    __syncthreads();   // once, before any gll traffic

    for (int ni = 0; ni < NPB; ++ni) {
        const int n = ng * NPB + ni;
        const float* Wn = W + (size_t)n * D_IN * MD + jbase;

        float acc[BB][4];
#pragma unroll
        for (int b = 0; b < BB; ++b) {
            acc[b][0] = 0.f; acc[b][1] = 0.f; acc[b][2] = 0.f; acc[b][3] = 0.f;
        }

        // stage tile tk into wb[pb]: wave wid stages a-row 'wid' of the tile,
        // 4 chunks of 1 KB (lds dest wave-uniform base + lane*16, m104).
        auto stage = [&](int tk, int pb) {
#pragma unroll
            for (int q = 0; q < 4; ++q) {
                const float* g = Wn + (size_t)(tk * TA + wid) * MD + q * 256 + lane * 4;
                float* l = &wb[pb][wid * 1024 + q * 256];
                gload16(g, l);
            }
        };
        auto compute = [&](int tk, int pb) {
#pragma unroll
            for (int al = 0; al < TA; ++al) {
                const int a = tk * TA + al;
                const float4 w = *reinterpret_cast<const float4*>(&wb[pb][al * 1024 + t * 4]);
                const float4* xa = reinterpret_cast<const float4*>(xs + (ni * D_IN + a) * BB);
                const float4 x0 = xa[0], x1 = xa[1], x2 = xa[2], x3 = xa[3];
                const float xv[BB] = {x0.x, x0.y, x0.z, x0.w, x1.x, x1.y, x1.z, x1.w,
                                      x2.x, x2.y, x2.z, x2.w, x3.x, x3.y, x3.z, x3.w};
#pragma unroll
                for (int b = 0; b < BB; ++b) {
                    acc[b][0] = fmaf(xv[b], w.x, acc[b][0]);
                    acc[b][1] = fmaf(xv[b], w.y, acc[b][1]);
                    acc[b][2] = fmaf(xv[b], w.z, acc[b][2]);
                    acc[b][3] = fmaf(xv[b], w.w, acc[b][3]);
                }
            }
        };

        stage(0, 0);
        stage(1, 1);
        VM4;                                    // tile0 resident (4 newest = tile1 ok)
        __builtin_amdgcn_sched_barrier(0);
        __builtin_amdgcn_s_barrier();

        for (int tk = 0; tk < NT; ++tk) {
            compute(tk, tk & 1);
            __builtin_amdgcn_s_barrier();       // all waves done reading wb[tk&1]
            if (tk < NT - 2) {
                stage(tk + 2, tk & 1);          // refill the buffer just freed
                VM4;                            // tile tk+1 resident; tk+2 in flight
            } else if (tk == NT - 2) {
                VM0;                            // last tile resident
            }
            if (tk < NT - 1) {
                __builtin_amdgcn_sched_barrier(0);
                __builtin_amdgcn_s_barrier();   // staged data visible to all waves
            }
        }

#pragma unroll
        for (int b = 0; b < BB; ++b) {
            union { __hip_bfloat16 h[4]; uint2 u; } pk;
            pk.h[0] = __float2bfloat16(acc[b][0]);
            pk.h[1] = __float2bfloat16(acc[b][1]);
            pk.h[2] = __float2bfloat16(acc[b][2]);
            pk.h[3] = __float2bfloat16(acc[b][3]);
            votes4[(((size_t)b * N_IN + n) * MD + j) >> 2] = pk.u;
        }
        if (ni == 0) __builtin_amdgcn_s_barrier();  // don't let next n's stage race last compute
    }
}

// -------- Pass ncv-part: ncv_part[nh][b][j] = sum over 64 n of votes (fp32) --------
__global__ __launch_bounds__(256) void pass_ncv_part(
    const uint32_t* __restrict__ votes2, float* __restrict__ ncv_part)
{
    const int t = threadIdx.x;
    const int jc = blockIdx.x;   // 0..7
    const int nh = blockIdx.y;   // 0..3
    const int b  = blockIdx.z;   // 0..15
    const int j = jc * 1024 + t * 4;

    const uint2* vp = reinterpret_cast<const uint2*>(votes2) +
                      ((((size_t)b * N_IN + (size_t)nh * 64) * MD + j) >> 2);
    float s0 = 0.f, s1 = 0.f, s2 = 0.f, s3 = 0.f;
#pragma unroll 8
    for (int n = 0; n < 64; ++n) {
        const uint2 u = vp[(size_t)n * (MD / 4)];
        s0 += __uint_as_float(u.x << 16);
        s1 += __uint_as_float(u.x & 0xffff0000u);
        s2 += __uint_as_float(u.y << 16);
        s3 += __uint_as_float(u.y & 0xffff0000u);
    }
    float4 o; o.x = s0; o.y = s1; o.z = s2; o.w = s3;
    *reinterpret_cast<float4*>(ncv_part + ((size_t)nh * BB + b) * MD + j) = o;
}

// ---------------- Pass 3: amean + scores -> softmax -> qk -> partial reduce ----------
__global__ __launch_bounds__(256) void pass3_route(
    const __hip_bfloat16* __restrict__ votes, const float* __restrict__ ncv_part,
    const float* __restrict__ act, float* __restrict__ out_part,
    float* __restrict__ next_act_out, float* __restrict__ qk_out)
{
    __shared__ float red[4];
    __shared__ float aw[4];
    const int t = threadIdx.x;
    const int b = blockIdx.x;
    const int nc = blockIdx.y;
    const int m = t >> 1;
    const int half = t & 1;

    float av = act[b * N_IN + t];
#pragma unroll
    for (int off = 32; off; off >>= 1) av += __shfl_xor(av, off);
    if ((t & 63) == 0) aw[t >> 6] = av;
    __syncthreads();
    const float amean = (aw[0] + aw[1] + aw[2] + aw[3]) * (1.f / 256.f);
    const float qs = amean / (amean + 1e-10f);
    if (nc == 0 && half == 0) next_act_out[b * N_OUT + m] = amean;

    float nv[32], oacc[32];
    {
        const float4* p0 = reinterpret_cast<const float4*>(ncv_part + ((size_t)0 * BB + b) * MD + t * 32);
        const float4* p1 = reinterpret_cast<const float4*>(ncv_part + ((size_t)1 * BB + b) * MD + t * 32);
        const float4* p2 = reinterpret_cast<const float4*>(ncv_part + ((size_t)2 * BB + b) * MD + t * 32);
        const float4* p3 = reinterpret_cast<const float4*>(ncv_part + ((size_t)3 * BB + b) * MD + t * 32);
#pragma unroll
        for (int q = 0; q < 8; ++q) {
            const float4 a0 = p0[q], a1 = p1[q], a2 = p2[q], a3 = p3[q];
            nv[4 * q + 0] = (a0.x + a1.x) + (a2.x + a3.x);
            nv[4 * q + 1] = (a0.y + a1.y) + (a2.y + a3.y);
            nv[4 * q + 2] = (a0.z + a1.z) + (a2.z + a3.z);
            nv[4 * q + 3] = (a0.w + a1.w) + (a2.w + a3.w);
        }
#pragma unroll
        for (int i = 0; i < 32; ++i) { nv[i] *= (1.f / (float)N_OUT); oacc[i] = 0.f; }
    }

    const uint4* vbase = reinterpret_cast<const uint4*>(
        votes + (size_t)b * ((size_t)N_IN * MD) + (size_t)(nc * 8) * MD + t * 32);
    const size_t nstride = MD / 8;  // uint4 units per n

    uint4 buf[4];
#pragma unroll
    for (int q = 0; q < 4; ++q) buf[q] = vbase[q];

    for (int ni = 0; ni < 8; ++ni) {
        const int n = nc * 8 + ni;
        float vv[32];
#pragma unroll
        for (int q = 0; q < 4; ++q) {
            const uint32_t ww[4] = {buf[q].x, buf[q].y, buf[q].z, buf[q].w};
#pragma unroll
            for (int k = 0; k < 4; ++k) {
                vv[8 * q + 2 * k]     = __uint_as_float(ww[k] << 16);
                vv[8 * q + 2 * k + 1] = __uint_as_float(ww[k] & 0xffff0000u);
            }
        }
        if (ni < 7) {
            const uint4* vn = vbase + (size_t)(ni + 1) * nstride;
#pragma unroll
            for (int q = 0; q < 4; ++q) buf[q] = vn[q];
        }

        float p0 = 0.f, p1 = 0.f, p2 = 0.f, p3 = 0.f;
#pragma unroll
        for (int i = 0; i < 8; ++i) {
            p0 = fmaf(vv[4 * i + 0], nv[4 * i + 0], p0);
            p1 = fmaf(vv[4 * i + 1], nv[4 * i + 1], p1);
            p2 = fmaf(vv[4 * i + 2], nv[4 * i + 2], p2);
            p3 = fmaf(vv[4 * i + 3], nv[4 * i + 3], p3);
        }
        float sp = (p0 + p1) + (p2 + p3);
        sp += __shfl_xor(sp, 1);
        sp *= 0.125f; // 1/sqrt(D_OUT)

        const float p = __expf(sp);   // |scores| << 88, no max-shift needed
        float s = p;
#pragma unroll
        for (int off = 32; off; off >>= 1) s += __shfl_xor(s, off);
        if ((t & 63) == 0) red[t >> 6] = s;
        __syncthreads();
        const float ssum = (red[0] + red[1] + red[2] + red[3]) * 0.5f;
        __syncthreads();

        const float qk = (p / ssum) * qs;
        if (half == 0) qk_out[((size_t)(b * N_IN + n) << 7) + m] = qk;

        const float c = qk * act[b * N_IN + n];
#pragma unroll
        for (int i = 0; i < 32; ++i) oacc[i] = fmaf(c, vv[i], oacc[i]);
    }

    float4* op = reinterpret_cast<float4*>(out_part + ((size_t)nc * BB + b) * MD + t * 32);
#pragma unroll
    for (int q = 0; q < 8; ++q) {
        float4 o; o.x = oacc[4 * q]; o.y = oacc[4 * q + 1];
        o.z = oacc[4 * q + 2]; o.w = oacc[4 * q + 3];
        op[q] = o;
    }
}

// ---------------- Combine: out0[b][j] = sum over 32 nc partials ----------------
__global__ __launch_bounds__(256) void combine_out0(
    const float* __restrict__ out_part, float* __restrict__ out0)
{
    const int idx = blockIdx.x * 256 + threadIdx.x;  // 32768 float4s
    const int b = idx >> 11;          // /2048
    const int v4 = idx & 2047;
    const float4* p = reinterpret_cast<const float4*>(out_part);
    float4 s = {0.f, 0.f, 0.f, 0.f};
#pragma unroll 8
    for (int nc = 0; nc < NCH; ++nc) {
        const float4 f = p[((size_t)nc * BB + b) * (MD / 4) + v4];
        s.x += f.x; s.y += f.y; s.z += f.z; s.w += f.w;
    }
    reinterpret_cast<float4*>(out0)[idx] = s;
}

extern "C" void kernel_launch(void* const* d_in, const int* in_sizes, int n_in,
                              void* d_out, int out_size, void* d_ws, size_t ws_size,
                              hipStream_t stream)
{
    const float* x   = (const float*)d_in[0];   // [16,256,128]
    const float* act = (const float*)d_in[1];   // [16,256]
    const float* W   = (const float*)d_in[2];   // [256,128,128,64]

    float* out      = (float*)d_out;
    float* out0     = out;                        // [16,128,64]  = 131072 elements
    float* next_act = out + 131072;               // [16,128]     = 2048
    float* qk_out   = out + 131072 + 2048;        // [16,256,128] = 524288

    // ws layout: votes bf16 64 MiB | ncv_part 2 MiB | out_part 16 MiB | xT 2 MiB
    __hip_bfloat16* votes = (__hip_bfloat16*)d_ws;
    float* ncv_part = (float*)((char*)d_ws + (size_t)67108864);
    float* out_part = (float*)((char*)d_ws + (size_t)67108864 + 2097152);
    float* xT       = (float*)((char*)d_ws + (size_t)67108864 + 2097152 + 16777216);

    pass0_xT<<<2048, 256, 0, stream>>>(x, xT);
    pass1_votes<<<dim3(8, 128), 256, 0, stream>>>(xT, W, (uint2*)votes);
    pass_ncv_part<<<dim3(8, 4, 16), 256, 0, stream>>>((const uint32_t*)votes, ncv_part);
    pass3_route<<<dim3(16, NCH), 256, 0, stream>>>(votes, ncv_part, act, out_part,
                                                   next_act, qk_out);
    combine_out0<<<128, 256, 0, stream>>>(out_part, out0);
}

// Round 15
// 258.675 us; speedup vs baseline: 1.7142x; 1.0928x over previous
//
#include <hip/hip_runtime.h>
#include <hip/hip_bf16.h>
#include <cstdint>

// CapsuleFC: B=16, N_IN=256, D_IN=128, N_OUT=128, D_OUT=64
// votes[b,n,m,d] = sum_a x[b,n,a] * W[n,a,m,d]        (W is 1 GiB fp32 -> HBM-bound)
// ncv[b,m,d]    = (sum_n votes) / N_OUT
// scores[b,n,m] = (1/8) * sum_d votes * ncv
// qk            = softmax_m(scores) * amean_b/(amean_b+1e-10)
// out0[b,m,d]   = sum_n qk * act[b,n] * votes
//
// Ledger: pass1=222us vs 171us pure-read probe (R12). Falsified: queue depth
// (R9), VALU count (R10), occupancy (R11), DMA-staged W (R13).
// R15 = R14 retry (fixed compile): NON-TEMPORAL votes stores via uint64_t
// (builtin rejects HIP uint2 class type) -> kill L2 dirty-line writeback
// interleave with the W read stream.

#define BB 16
#define N_IN 256
#define D_IN 128
#define N_OUT 128
#define D_OUT 64
#define MD (N_OUT * D_OUT) /* 8192 */
#define NPB 2               /* n per block in pass1 */
#define NCH 32              /* n-chunks in pass3 (8 n each) */

// ---------------- Pass 0: transpose x -> xT[n][a][b] (b contiguous) ----------------
__global__ __launch_bounds__(256) void pass0_xT(
    const float* __restrict__ x, float* __restrict__ xT)
{
    const int idx = blockIdx.x * 256 + threadIdx.x;  // 524288 total
    const int b = idx & 15;
    const int a = (idx >> 4) & 127;
    const int n = idx >> 11;
    xT[idx] = x[((size_t)b * N_IN + n) * D_IN + a];  // write coalesced
}

// ---------------- Pass 1: votes (bf16x4), x staged in LDS, nt stores ---------------
// grid (8 j-chunks of 1024, 128 n-groups of 2), block 256, 4 blocks/CU.
__global__ __launch_bounds__(256, 4) void pass1_votes(
    const float* __restrict__ xT, const float* __restrict__ W,
    uint64_t* __restrict__ votes4)
{
    __shared__ float xs[NPB * D_IN * BB]; // 16 KB
    const int t = threadIdx.x;
    const int chunk = blockIdx.x;   // 0..7
    const int ng = blockIdx.y;      // 0..127
    const int j = chunk * 1024 + t * 4;

    {
        const float4* src = reinterpret_cast<const float4*>(xT + ((size_t)ng * NPB << 11));
        float4* dst = reinterpret_cast<float4*>(xs);
#pragma unroll
        for (int r = 0; r < 4; ++r) dst[r * 256 + t] = src[r * 256 + t];
    }
    __syncthreads();

    for (int ni = 0; ni < NPB; ++ni) {
        const int n = ng * NPB + ni;
        const float4* __restrict__ Wp =
            reinterpret_cast<const float4*>(W + (size_t)n * D_IN * MD + j);

        float acc[BB][4];
#pragma unroll
        for (int b = 0; b < BB; ++b) {
            acc[b][0] = 0.f; acc[b][1] = 0.f; acc[b][2] = 0.f; acc[b][3] = 0.f;
        }

#pragma unroll 4
        for (int a = 0; a < D_IN; ++a) {
            const float4 w = Wp[(size_t)a * (MD / 4)];   // 1 KB/wave, coalesced
            const float4* xa = reinterpret_cast<const float4*>(xs + (ni * D_IN + a) * BB);
            const float4 x0 = xa[0], x1 = xa[1], x2 = xa[2], x3 = xa[3];
            const float xv[BB] = {x0.x, x0.y, x0.z, x0.w, x1.x, x1.y, x1.z, x1.w,
                                  x2.x, x2.y, x2.z, x2.w, x3.x, x3.y, x3.z, x3.w};
#pragma unroll
            for (int b = 0; b < BB; ++b) {
                acc[b][0] = fmaf(xv[b], w.x, acc[b][0]);
                acc[b][1] = fmaf(xv[b], w.y, acc[b][1]);
                acc[b][2] = fmaf(xv[b], w.z, acc[b][2]);
                acc[b][3] = fmaf(xv[b], w.w, acc[b][3]);
            }
        }

#pragma unroll
        for (int b = 0; b < BB; ++b) {
            union { __hip_bfloat16 h[4]; uint64_t u; } pk;
            pk.h[0] = __float2bfloat16(acc[b][0]);
            pk.h[1] = __float2bfloat16(acc[b][1]);
            pk.h[2] = __float2bfloat16(acc[b][2]);
            pk.h[3] = __float2bfloat16(acc[b][3]);
            // NON-TEMPORAL: stream past L2, no dirty-writeback interleave with W reads
            __builtin_nontemporal_store(pk.u, &votes4[(((size_t)b * N_IN + n) * MD + j) >> 2]);
        }
    }
}

// -------- Pass ncv-part: ncv_part[nh][b][j] = sum over 64 n of votes (fp32) --------
__global__ __launch_bounds__(256) void pass_ncv_part(
    const uint32_t* __restrict__ votes2, float* __restrict__ ncv_part)
{
    const int t = threadIdx.x;
    const int jc = blockIdx.x;   // 0..7
    const int nh = blockIdx.y;   // 0..3
    const int b  = blockIdx.z;   // 0..15
    const int j = jc * 1024 + t * 4;

    const uint2* vp = reinterpret_cast<const uint2*>(votes2) +
                      ((((size_t)b * N_IN + (size_t)nh * 64) * MD + j) >> 2);
    float s0 = 0.f, s1 = 0.f, s2 = 0.f, s3 = 0.f;
#pragma unroll 8
    for (int n = 0; n < 64; ++n) {
        const uint2 u = vp[(size_t)n * (MD / 4)];
        s0 += __uint_as_float(u.x << 16);
        s1 += __uint_as_float(u.x & 0xffff0000u);
        s2 += __uint_as_float(u.y << 16);
        s3 += __uint_as_float(u.y & 0xffff0000u);
    }
    float4 o; o.x = s0; o.y = s1; o.z = s2; o.w = s3;
    *reinterpret_cast<float4*>(ncv_part + ((size_t)nh * BB + b) * MD + j) = o;
}

// ---------------- Pass 3: amean + scores -> softmax -> qk -> partial reduce ----------
__global__ __launch_bounds__(256) void pass3_route(
    const __hip_bfloat16* __restrict__ votes, const float* __restrict__ ncv_part,
    const float* __restrict__ act, float* __restrict__ out_part,
    float* __restrict__ next_act_out, float* __restrict__ qk_out)
{
    __shared__ float red[4];
    __shared__ float aw[4];
    const int t = threadIdx.x;
    const int b = blockIdx.x;
    const int nc = blockIdx.y;
    const int m = t >> 1;
    const int half = t & 1;

    float av = act[b * N_IN + t];
#pragma unroll
    for (int off = 32; off; off >>= 1) av += __shfl_xor(av, off);
    if ((t & 63) == 0) aw[t >> 6] = av;
    __syncthreads();
    const float amean = (aw[0] + aw[1] + aw[2] + aw[3]) * (1.f / 256.f);
    const float qs = amean / (amean + 1e-10f);
    if (nc == 0 && half == 0) next_act_out[b * N_OUT + m] = amean;

    float nv[32], oacc[32];
    {
        const float4* p0 = reinterpret_cast<const float4*>(ncv_part + ((size_t)0 * BB + b) * MD + t * 32);
        const float4* p1 = reinterpret_cast<const float4*>(ncv_part + ((size_t)1 * BB + b) * MD + t * 32);
        const float4* p2 = reinterpret_cast<const float4*>(ncv_part + ((size_t)2 * BB + b) * MD + t * 32);
        const float4* p3 = reinterpret_cast<const float4*>(ncv_part + ((size_t)3 * BB + b) * MD + t * 32);
#pragma unroll
        for (int q = 0; q < 8; ++q) {
            const float4 a0 = p0[q], a1 = p1[q], a2 = p2[q], a3 = p3[q];
            nv[4 * q + 0] = (a0.x + a1.x) + (a2.x + a3.x);
            nv[4 * q + 1] = (a0.y + a1.y) + (a2.y + a3.y);
            nv[4 * q + 2] = (a0.z + a1.z) + (a2.z + a3.z);
            nv[4 * q + 3] = (a0.w + a1.w) + (a2.w + a3.w);
        }
#pragma unroll
        for (int i = 0; i < 32; ++i) { nv[i] *= (1.f / (float)N_OUT); oacc[i] = 0.f; }
    }

    const uint4* vbase = reinterpret_cast<const uint4*>(
        votes + (size_t)b * ((size_t)N_IN * MD) + (size_t)(nc * 8) * MD + t * 32);
    const size_t nstride = MD / 8;  // uint4 units per n

    uint4 buf[4];
#pragma unroll
    for (int q = 0; q < 4; ++q) buf[q] = vbase[q];

    for (int ni = 0; ni < 8; ++ni) {
        const int n = nc * 8 + ni;
        float vv[32];
#pragma unroll
        for (int q = 0; q < 4; ++q) {
            const uint32_t ww[4] = {buf[q].x, buf[q].y, buf[q].z, buf[q].w};
#pragma unroll
            for (int k = 0; k < 4; ++k) {
                vv[8 * q + 2 * k]     = __uint_as_float(ww[k] << 16);
                vv[8 * q + 2 * k + 1] = __uint_as_float(ww[k] & 0xffff0000u);
            }
        }
        if (ni < 7) {
            const uint4* vn = vbase + (size_t)(ni + 1) * nstride;
#pragma unroll
            for (int q = 0; q < 4; ++q) buf[q] = vn[q];
        }

        float p0 = 0.f, p1 = 0.f, p2 = 0.f, p3 = 0.f;
#pragma unroll
        for (int i = 0; i < 8; ++i) {
            p0 = fmaf(vv[4 * i + 0], nv[4 * i + 0], p0);
            p1 = fmaf(vv[4 * i + 1], nv[4 * i + 1], p1);
            p2 = fmaf(vv[4 * i + 2], nv[4 * i + 2], p2);
            p3 = fmaf(vv[4 * i + 3], nv[4 * i + 3], p3);
        }
        float sp = (p0 + p1) + (p2 + p3);
        sp += __shfl_xor(sp, 1);
        sp *= 0.125f; // 1/sqrt(D_OUT)

        const float p = __expf(sp);   // |scores| << 88, no max-shift needed
        float s = p;
#pragma unroll
        for (int off = 32; off; off >>= 1) s += __shfl_xor(s, off);
        if ((t & 63) == 0) red[t >> 6] = s;
        __syncthreads();
        const float ssum = (red[0] + red[1] + red[2] + red[3]) * 0.5f;
        __syncthreads();

        const float qk = (p / ssum) * qs;
        if (half == 0) qk_out[((size_t)(b * N_IN + n) << 7) + m] = qk;

        const float c = qk * act[b * N_IN + n];
#pragma unroll
        for (int i = 0; i < 32; ++i) oacc[i] = fmaf(c, vv[i], oacc[i]);
    }

    float4* op = reinterpret_cast<float4*>(out_part + ((size_t)nc * BB + b) * MD + t * 32);
#pragma unroll
    for (int q = 0; q < 8; ++q) {
        float4 o; o.x = oacc[4 * q]; o.y = oacc[4 * q + 1];
        o.z = oacc[4 * q + 2]; o.w = oacc[4 * q + 3];
        op[q] = o;
    }
}

// ---------------- Combine: out0[b][j] = sum over 32 nc partials ----------------
__global__ __launch_bounds__(256) void combine_out0(
    const float* __restrict__ out_part, float* __restrict__ out0)
{
    const int idx = blockIdx.x * 256 + threadIdx.x;  // 32768 float4s
    const int b = idx >> 11;          // /2048
    const int v4 = idx & 2047;
    const float4* p = reinterpret_cast<const float4*>(out_part);
    float4 s = {0.f, 0.f, 0.f, 0.f};
#pragma unroll 8
    for (int nc = 0; nc < NCH; ++nc) {
        const float4 f = p[((size_t)nc * BB + b) * (MD / 4) + v4];
        s.x += f.x; s.y += f.y; s.z += f.z; s.w += f.w;
    }
    reinterpret_cast<float4*>(out0)[idx] = s;
}

extern "C" void kernel_launch(void* const* d_in, const int* in_sizes, int n_in,
                              void* d_out, int out_size, void* d_ws, size_t ws_size,
                              hipStream_t stream)
{
    const float* x   = (const float*)d_in[0];   // [16,256,128]
    const float* act = (const float*)d_in[1];   // [16,256]
    const float* W   = (const float*)d_in[2];   // [256,128,128,64]

    float* out      = (float*)d_out;
    float* out0     = out;                        // [16,128,64]  = 131072 elements
    float* next_act = out + 131072;               // [16,128]     = 2048
    float* qk_out   = out + 131072 + 2048;        // [16,256,128] = 524288

    // ws layout: votes bf16 64 MiB | ncv_part 2 MiB | out_part 16 MiB | xT 2 MiB
    __hip_bfloat16* votes = (__hip_bfloat16*)d_ws;
    float* ncv_part = (float*)((char*)d_ws + (size_t)67108864);
    float* out_part = (float*)((char*)d_ws + (size_t)67108864 + 2097152);
    float* xT       = (float*)((char*)d_ws + (size_t)67108864 + 2097152 + 16777216);

    pass0_xT<<<2048, 256, 0, stream>>>(x, xT);
    pass1_votes<<<dim3(8, 128), 256, 0, stream>>>(xT, W, (uint64_t*)votes);
    pass_ncv_part<<<dim3(8, 4, 16), 256, 0, stream>>>((const uint32_t*)votes, ncv_part);
    pass3_route<<<dim3(16, NCH), 256, 0, stream>>>(votes, ncv_part, act, out_part,
                                                   next_act, qk_out);
    combine_out0<<<128, 256, 0, stream>>>(out_part, out0);
}